// Round 1
// 106.873 us; speedup vs baseline: 1.0448x; 1.0448x over previous
//
#include <hip/hip_runtime.h>
#include <math.h>

// NT-Xent (SimCLR) loss. B=4096, D=256, T=0.5.
// zb = bf16(normalize(concat(emb_i, emb_j)))  [8192][256]
// sim = zb@zb^T via MFMA bf16; exp(2*sim) symmetric -> upper-triangle tiles
// only. Tile (bx,by) bx<=by: rowsums -> denomP[by][rows of bx], colsums
// (bx<by) -> denomP[bx][cols of by]. Diagonal (grow==gcol) skipped globally.
// pos_k = sim[k][k+4096] extracted from tiles with by == bx+32.
// loss = (1/8192) * ( 4*sum_k pos[k] - sum_r log(denom[r]) )
//
// R1: (a) T2 LDS XOR-swizzle applied via pre-swizzled GLOBAL source chunk
//     (global_load_lds writes linearly; rule #21 both-sides) + swizzled
//     ds_read chunk -> kills the 16-way bank conflict (6.39M cycles/dispatch).
//     (b) T3-minimum 2-phase pipeline: double-buffered As/Bs (64 KB), stage
//     tile k+1 before computing tile k, one __syncthreads per K-step.

#define NROWS 8192
#define NHALF 4096
#define DIM   256
#define BM    128
#define BN    128
#define BK    64
#define NCB   (NROWS / BN)          // 64 row/col blocks
#define NTRI  (NCB * (NCB + 1) / 2) // 2080 triangle tiles

typedef __attribute__((ext_vector_type(8))) short bf16x8;
typedef __attribute__((ext_vector_type(4))) float f32x4;

static __device__ __forceinline__ unsigned short f2bf(float x) {
  unsigned int u = __float_as_uint(x);
  unsigned int r = (u + 0x7FFFu + ((u >> 16) & 1u)) >> 16;
  return (unsigned short)r;
}

// ------------------------------------------- normalize (also zeroes out[0])
__global__ __launch_bounds__(256) void normalize_kernel(
    const float* __restrict__ emb_i, const float* __restrict__ emb_j,
    unsigned short* __restrict__ zb, float* __restrict__ out) {
  if (blockIdx.x == 0 && threadIdx.x == 0) out[0] = 0.f;
  int w = threadIdx.x >> 6, lane = threadIdx.x & 63;
  int row = blockIdx.x * 4 + w;
  const float* src = (row < NHALF) ? (emb_i + (size_t)row * DIM)
                                   : (emb_j + (size_t)(row - NHALF) * DIM);
  float4 v = ((const float4*)src)[lane];
  float ss = v.x * v.x + v.y * v.y + v.z * v.z + v.w * v.w;
  #pragma unroll
  for (int off = 32; off; off >>= 1) ss += __shfl_down(ss, off, 64);
  float total = __shfl(ss, 0, 64);
  float inv = 1.0f / fmaxf(sqrtf(total), 1e-12f);
  ushort4 o;
  o.x = f2bf(v.x * inv); o.y = f2bf(v.y * inv);
  o.z = f2bf(v.z * inv); o.w = f2bf(v.w * inv);
  ((ushort4*)&zb[(size_t)row * DIM])[lane] = o;
}

// ------------------------------------------------ MFMA GEMM + exp + sums
__global__ __launch_bounds__(256) void denom_kernel(
    const unsigned short* __restrict__ zb, float* __restrict__ denomP,
    float* __restrict__ posv) {
  __shared__ unsigned short As[2][BM * BK];  // 2 x 16 KB
  __shared__ unsigned short Bs[2][BN * BK];  // 2 x 16 KB

  // decode triangle tile id -> (bx, by), bx <= by
  int t = blockIdx.x;
  int by = (int)((sqrtf(8.0f * (float)t + 1.0f) - 1.0f) * 0.5f);
  while ((by + 1) * (by + 2) / 2 <= t) ++by;
  while (by * (by + 1) / 2 > t) --by;
  int bx = t - by * (by + 1) / 2;

  const int tid = threadIdx.x;
  const int w = tid >> 6;
  const int lane = tid & 63;
  const int wr = w >> 1, wc = w & 1;  // 2x2 wave grid, 64x64 each
  const int quad = lane >> 4;
  const int m16 = lane & 15;
  const int row0 = bx * BM;
  const int col0 = by * BN;

  const unsigned short* zbA = zb + (size_t)row0 * DIM;
  const unsigned short* zbB = zb + (size_t)col0 * DIM;
  // Pre-swizzled global chunk: LDS dest is linear (lane*16B), so lane l holds
  // LDS row rbase+(l>>3), chunk (l&7). Since rbase%8==0, row&7 == l>>3;
  // store global chunk (l&7)^(l>>3) there -> read back with chunk^(row&7).
  const int swz = ((lane & 7) ^ (lane >> 3)) * 8;  // shorts within K-slice

  f32x4 acc[4][4];
  #pragma unroll
  for (int i = 0; i < 4; ++i)
    #pragma unroll
    for (int j = 0; j < 4; ++j) {
      f32x4 z4 = {0.f, 0.f, 0.f, 0.f};
      acc[i][j] = z4;
    }

  auto stage = [&](int b, int kc) {
    #pragma unroll
    for (int tt = 0; tt < 4; ++tt) {
      int rbase = w * 32 + tt * 8;
      int gr = rbase + (lane >> 3);
      int gk = kc + swz;
      __builtin_amdgcn_global_load_lds(
          (const __attribute__((address_space(1))) unsigned int*)
              &zbA[(size_t)gr * DIM + gk],
          (__attribute__((address_space(3))) unsigned int*)&As[b][rbase * BK],
          16, 0, 0);
      __builtin_amdgcn_global_load_lds(
          (const __attribute__((address_space(1))) unsigned int*)
              &zbB[(size_t)gr * DIM + gk],
          (__attribute__((address_space(3))) unsigned int*)&Bs[b][rbase * BK],
          16, 0, 0);
    }
  };

  auto compute = [&](int b) {
    #pragma unroll
    for (int ks = 0; ks < BK; ks += 32) {
      bf16x8 af[4], bfr[4];
      #pragma unroll
      for (int i = 0; i < 4; ++i) {
        int row = wr * 64 + i * 16 + m16;
        af[i] = *(const bf16x8*)
            &As[b][row * BK + ((((ks >> 3) + quad) ^ (m16 & 7)) * 8)];
      }
      #pragma unroll
      for (int j = 0; j < 4; ++j) {
        int row = wc * 64 + j * 16 + m16;
        bfr[j] = *(const bf16x8*)
            &Bs[b][row * BK + ((((ks >> 3) + quad) ^ (m16 & 7)) * 8)];
      }
      #pragma unroll
      for (int i = 0; i < 4; ++i)
        #pragma unroll
        for (int j = 0; j < 4; ++j)
          acc[i][j] = __builtin_amdgcn_mfma_f32_16x16x32_bf16(
              af[i], bfr[j], acc[i][j], 0, 0, 0);
    }
  };

  // 2-phase pipeline: stage(next) issued before compute(cur); one
  // vmcnt(0)-draining __syncthreads per K-step covers both the staged
  // buffer and the cross-iteration WAR on the buffer being overwritten.
  stage(0, 0);
  __syncthreads();
  #pragma unroll
  for (int kc = BK; kc < DIM; kc += BK) {
    const int nb = (kc >> 6) & 1;  // 64->1, 128->0, 192->1
    stage(nb, kc);
    compute(nb ^ 1);
    __syncthreads();
  }
  compute(1);  // (DIM/BK - 1) & 1

  // pos extraction: only tiles with col0 == row0 + NHALF hold pair elements.
  if (col0 - row0 == NHALF) {
    #pragma unroll
    for (int i = 0; i < 4; ++i)
      #pragma unroll
      for (int j = 0; j < 4; ++j) {
        int gcol = col0 + wc * 64 + j * 16 + m16;
        #pragma unroll
        for (int r = 0; r < 4; ++r) {
          int grow = row0 + wr * 64 + i * 16 + quad * 4 + r;
          if (gcol - grow == NHALF) posv[grow] = acc[i][j][r];
        }
      }
  }

  // Unified epilogue: e = exp(2*sim); skip the global diagonal (grow==gcol,
  // only occurs in bx==by tiles); accumulate row and column sums.
  // C layout (16x16x32): col = wc*64 + j*16 + m16,
  //                      row = wr*64 + i*16 + quad*4 + r.
  float rs[4][4];
  float cs[4] = {0.f, 0.f, 0.f, 0.f};
  #pragma unroll
  for (int i = 0; i < 4; ++i)
    #pragma unroll
    for (int r = 0; r < 4; ++r) rs[i][r] = 0.f;

  #pragma unroll
  for (int i = 0; i < 4; ++i)
    #pragma unroll
    for (int j = 0; j < 4; ++j) {
      int gcol = col0 + wc * 64 + j * 16 + m16;
      #pragma unroll
      for (int r = 0; r < 4; ++r) {
        int grow = row0 + wr * 64 + i * 16 + quad * 4 + r;
        float e = (grow == gcol) ? 0.f : __expf(2.0f * acc[i][j][r]);
        rs[i][r] += e;
        cs[j] += e;
      }
    }

  // As[0] is dead during/after the final compute (it ran on buffer 1).
  float* red = (float*)As;  // 512 floats: [0,256) rowsums, [256,512) colsums

  // rowsum: reduce across the 16 column lanes (same quad)
  #pragma unroll
  for (int i = 0; i < 4; ++i)
    #pragma unroll
    for (int r = 0; r < 4; ++r) {
      float v = rs[i][r];
      v += __shfl_xor(v, 1, 16);
      v += __shfl_xor(v, 2, 16);
      v += __shfl_xor(v, 4, 16);
      v += __shfl_xor(v, 8, 16);
      if (m16 == 0) red[wc * 128 + wr * 64 + i * 16 + quad * 4 + r] = v;
    }
  // colsum: reduce across the 4 quads
  #pragma unroll
  for (int j = 0; j < 4; ++j) {
    float v = cs[j];
    v += __shfl_xor(v, 16, 64);
    v += __shfl_xor(v, 32, 64);
    if (quad == 0) red[256 + wr * 128 + wc * 64 + j * 16 + m16] = v;
  }
  __syncthreads();

  if (tid < 128) {
    denomP[(size_t)by * NROWS + row0 + tid] = red[tid] + red[128 + tid];
  } else if (bx != by) {
    int c = tid - 128;
    denomP[(size_t)bx * NROWS + col0 + c] = red[256 + c] + red[384 + c];
  }
}

// -------------------- denom slots -> -log; + 4*pos; atomic into loss
__global__ __launch_bounds__(256) void reduce_kernel(
    const float* __restrict__ denomP, const float* __restrict__ posv,
    float* __restrict__ out) {
  int tid = threadIdx.x;
  int r = blockIdx.x * 256 + tid;  // 32 blocks cover 8192 rows
  float s = 0.f;
  #pragma unroll 8
  for (int b = 0; b < NCB; ++b) s += denomP[(size_t)b * NROWS + r];
  float v = -logf(s);
  if (r < NHALF) v += 4.0f * posv[r];
  #pragma unroll
  for (int off = 32; off; off >>= 1) v += __shfl_down(v, off, 64);
  __shared__ float s4[4];
  if ((tid & 63) == 0) s4[tid >> 6] = v;
  __syncthreads();
  if (tid == 0)
    atomicAdd(out, (s4[0] + s4[1] + s4[2] + s4[3]) * (1.0f / 8192.0f));
}

extern "C" void kernel_launch(void* const* d_in, const int* in_sizes, int n_in,
                              void* d_out, int out_size, void* d_ws,
                              size_t ws_size, hipStream_t stream) {
  const float* emb_i = (const float*)d_in[0];
  const float* emb_j = (const float*)d_in[1];
  unsigned short* zb = (unsigned short*)d_ws;            // 4 MB
  float* denomP = (float*)(zb + (size_t)NROWS * DIM);    // 64*8192 f32 (2 MB)
  float* posv = denomP + (size_t)NCB * NROWS;            // 4096 f32
  float* out = (float*)d_out;

  normalize_kernel<<<NROWS / 4, 256, 0, stream>>>(emb_i, emb_j, zb, out);
  denom_kernel<<<NTRI, 256, 0, stream>>>(zb, denomP, posv);
  reduce_kernel<<<NROWS / 256, 256, 0, stream>>>(denomP, posv, out);
}

// Round 2
// 99.850 us; speedup vs baseline: 1.1183x; 1.0703x over previous
//
#include <hip/hip_runtime.h>
#include <math.h>

// NT-Xent (SimCLR) loss. B=4096, D=256, T=0.5.
// R2: LDS/barrier pipeline DELETED from the GEMM. zb (4 MB) is L2-resident;
// normalize_kernel emits it in MFMA-fragment-native layout so denom_kernel
// loads fragments directly from global, perfectly coalesced (1 KB/instr):
//   zbF layout: rg = row>>4 (512 groups), ks = k>>5 (8 slices):
//     offset_shorts = rg*4096 + ks*512 + ((k>>3)&3)*128 + (row&15)*8 + (k&7)
//   -> lane (quad*16+m16) reads its 16 B a/b-frag at base + lane*16B.
// Inputs scaled by sqrt(2): acc = 2*sim -> __expf(acc) saves a mul/elem;
// posv holds 2*sim (reduce weight 2.0). Diagonal-tile epilogue specialized.
// No __syncthreads in the GEMM; only a 2 KB LDS buffer for the row/col
// reduction at the end. __launch_bounds__(256,3) -> 3 blocks/CU target.

#define NROWS 8192
#define NHALF 4096
#define DIM   256
#define BM    128
#define BN    128
#define NCB   (NROWS / BN)          // 64 row/col blocks
#define NTRI  (NCB * (NCB + 1) / 2) // 2080 triangle tiles

typedef __attribute__((ext_vector_type(8))) short bf16x8;
typedef __attribute__((ext_vector_type(4))) float f32x4;

static __device__ __forceinline__ unsigned short f2bf(float x) {
  unsigned int u = __float_as_uint(x);
  unsigned int r = (u + 0x7FFFu + ((u >> 16) & 1u)) >> 16;
  return (unsigned short)r;
}

// ---------------- normalize -> fragment-native layout (also zeroes out[0])
// One block per 16-row group (rg). Wave w handles rows m16 = w*4 .. w*4+3,
// one row per iteration (lane holds float4 at k = lane*4). Scatter the bf16
// into LDS in fragment layout, then copy 8 KB out linearly (coalesced).
__global__ __launch_bounds__(256) void normalize_kernel(
    const float* __restrict__ emb_i, const float* __restrict__ emb_j,
    unsigned short* __restrict__ zbF, float* __restrict__ out) {
  __shared__ unsigned short tile[16 * DIM];  // 8 KB
  if (blockIdx.x == 0 && threadIdx.x == 0) out[0] = 0.f;
  const int w = threadIdx.x >> 6, lane = threadIdx.x & 63;
  const int rg = blockIdx.x;
  #pragma unroll
  for (int rr = 0; rr < 4; ++rr) {
    const int m16 = w * 4 + rr;
    const int row = rg * 16 + m16;
    const float* src = (row < NHALF) ? (emb_i + (size_t)row * DIM)
                                     : (emb_j + (size_t)(row - NHALF) * DIM);
    float4 v = ((const float4*)src)[lane];
    float ss = v.x * v.x + v.y * v.y + v.z * v.z + v.w * v.w;
    #pragma unroll
    for (int off = 32; off; off >>= 1) ss += __shfl_down(ss, off, 64);
    float total = __shfl(ss, 0, 64);
    // sqrt(2) scale: downstream acc = 2*sim exactly what exp/pos need.
    float inv = 1.41421356237f / fmaxf(sqrtf(total), 1e-12f);
    ushort4 o;
    o.x = f2bf(v.x * inv); o.y = f2bf(v.y * inv);
    o.z = f2bf(v.z * inv); o.w = f2bf(v.w * inv);
    // k = lane*4 -> ks = lane>>3, quad = (lane>>1)&3, j = (lane&1)*4
    const int ks = lane >> 3, quad = (lane >> 1) & 3, jj = (lane & 1) * 4;
    *(ushort4*)&tile[ks * 512 + (quad * 16 + m16) * 8 + jj] = o;
  }
  __syncthreads();
  uint4* dst = (uint4*)(zbF + (size_t)rg * (16 * DIM));
  const uint4* srcT = (const uint4*)tile;
  dst[threadIdx.x] = srcT[threadIdx.x];
  dst[256 + threadIdx.x] = srcT[256 + threadIdx.x];
}

// ------------------------------------------------ MFMA GEMM + exp + sums
__global__ __launch_bounds__(256, 3) void denom_kernel(
    const unsigned short* __restrict__ zbF, float* __restrict__ denomP,
    float* __restrict__ posv) {
  __shared__ float red[512];  // 2 KB: [0,256) rowsums, [256,512) colsums

  // decode triangle tile id -> (bx, by), bx <= by
  int t = blockIdx.x;
  int by = (int)((sqrtf(8.0f * (float)t + 1.0f) - 1.0f) * 0.5f);
  while ((by + 1) * (by + 2) / 2 <= t) ++by;
  while (by * (by + 1) / 2 > t) --by;
  int bx = t - by * (by + 1) / 2;

  const int tid = threadIdx.x;
  const int w = tid >> 6;
  const int lane = tid & 63;
  const int wr = w >> 1, wc = w & 1;  // 2x2 wave grid, 64x64 each
  const int quad = lane >> 4;
  const int m16 = lane & 15;
  const int row0 = bx * BM;
  const int col0 = by * BN;

  // fragment base pointers: rg = bx*8 + wr*4 + i (A), by*8 + wc*4 + j (B);
  // lane's 16 B fragment sits at +lane*8 shorts; k-slice step = 512 shorts.
  const unsigned short* pA[4];
  const unsigned short* pB[4];
  #pragma unroll
  for (int i = 0; i < 4; ++i) {
    pA[i] = zbF + (size_t)(bx * 8 + wr * 4 + i) * 4096 + lane * 8;
    pB[i] = zbF + (size_t)(by * 8 + wc * 4 + i) * 4096 + lane * 8;
  }

  f32x4 acc[4][4];
  #pragma unroll
  for (int i = 0; i < 4; ++i)
    #pragma unroll
    for (int j = 0; j < 4; ++j) {
      f32x4 z4 = {0.f, 0.f, 0.f, 0.f};
      acc[i][j] = z4;
    }

#define LOADAB(A, B, ks)                                          \
  do {                                                            \
    _Pragma("unroll") for (int i = 0; i < 4; ++i) {               \
      A[i] = *(const bf16x8*)(pA[i] + (ks) * 512);                \
      B[i] = *(const bf16x8*)(pB[i] + (ks) * 512);                \
    }                                                             \
  } while (0)

#define MFMA16(A, B)                                              \
  do {                                                            \
    _Pragma("unroll") for (int i = 0; i < 4; ++i)                 \
        _Pragma("unroll") for (int j = 0; j < 4; ++j)             \
            acc[i][j] = __builtin_amdgcn_mfma_f32_16x16x32_bf16(  \
                A[i], B[j], acc[i][j], 0, 0, 0);                  \
  } while (0)

  bf16x8 aE[4], bE[4], aO[4], bO[4];
  LOADAB(aE, bE, 0);
  LOADAB(aO, bO, 1);
  #pragma unroll
  for (int k2 = 0; k2 < 4; ++k2) {
    MFMA16(aE, bE);
    if (k2 < 3) LOADAB(aE, bE, 2 * k2 + 2);
    MFMA16(aO, bO);
    if (k2 < 3) LOADAB(aO, bO, 2 * k2 + 3);
  }
#undef LOADAB
#undef MFMA16

  // pos extraction: only tiles with col0 == row0 + NHALF hold pair elements.
  // acc = 2*sim; posv stores 2*sim (reduce applies weight 2.0).
  if (col0 - row0 == NHALF) {
    #pragma unroll
    for (int i = 0; i < 4; ++i)
      #pragma unroll
      for (int j = 0; j < 4; ++j) {
        int gcol = col0 + wc * 64 + j * 16 + m16;
        #pragma unroll
        for (int r = 0; r < 4; ++r) {
          int grow = row0 + wr * 64 + i * 16 + quad * 4 + r;
          if (gcol - grow == NHALF) posv[grow] = acc[i][j][r];
        }
      }
  }

  // Epilogue: e = exp(acc) (acc = 2*sim). Diagonal tiles (bx==by, 64 of
  // 2080) pay the grow==gcol compare; off-diagonal tiles skip it entirely.
  float rs[4][4];
  float cs[4] = {0.f, 0.f, 0.f, 0.f};
  #pragma unroll
  for (int i = 0; i < 4; ++i)
    #pragma unroll
    for (int r = 0; r < 4; ++r) rs[i][r] = 0.f;

  if (bx != by) {
    #pragma unroll
    for (int i = 0; i < 4; ++i)
      #pragma unroll
      for (int j = 0; j < 4; ++j)
        #pragma unroll
        for (int r = 0; r < 4; ++r) {
          float e = __expf(acc[i][j][r]);
          rs[i][r] += e;
          cs[j] += e;
        }
  } else {
    #pragma unroll
    for (int i = 0; i < 4; ++i)
      #pragma unroll
      for (int j = 0; j < 4; ++j) {
        int gcol = col0 + wc * 64 + j * 16 + m16;
        #pragma unroll
        for (int r = 0; r < 4; ++r) {
          int grow = row0 + wr * 64 + i * 16 + quad * 4 + r;
          float e = (grow == gcol) ? 0.f : __expf(acc[i][j][r]);
          rs[i][r] += e;
          cs[j] += e;
        }
      }
  }

  // rowsum: reduce across the 16 column lanes (same quad)
  #pragma unroll
  for (int i = 0; i < 4; ++i)
    #pragma unroll
    for (int r = 0; r < 4; ++r) {
      float v = rs[i][r];
      v += __shfl_xor(v, 1, 16);
      v += __shfl_xor(v, 2, 16);
      v += __shfl_xor(v, 4, 16);
      v += __shfl_xor(v, 8, 16);
      if (m16 == 0) red[wc * 128 + wr * 64 + i * 16 + quad * 4 + r] = v;
    }
  // colsum: reduce across the 4 quads
  #pragma unroll
  for (int j = 0; j < 4; ++j) {
    float v = cs[j];
    v += __shfl_xor(v, 16, 64);
    v += __shfl_xor(v, 32, 64);
    if (quad == 0) red[256 + wr * 128 + wc * 64 + j * 16 + m16] = v;
  }
  __syncthreads();

  if (tid < 128) {
    denomP[(size_t)by * NROWS + row0 + tid] = red[tid] + red[128 + tid];
  } else if (bx != by) {
    int c = tid - 128;
    denomP[(size_t)bx * NROWS + col0 + c] = red[256 + c] + red[384 + c];
  }
}

// -------------------- denom slots -> -log; + 2*pos'; atomic into loss
__global__ __launch_bounds__(256) void reduce_kernel(
    const float* __restrict__ denomP, const float* __restrict__ posv,
    float* __restrict__ out) {
  int tid = threadIdx.x;
  int r = blockIdx.x * 256 + tid;  // 32 blocks cover 8192 rows
  float s = 0.f;
  #pragma unroll 8
  for (int b = 0; b < NCB; ++b) s += denomP[(size_t)b * NROWS + r];
  float v = -logf(s);
  if (r < NHALF) v += 2.0f * posv[r];  // posv = 2*sim; need 4*sim
  #pragma unroll
  for (int off = 32; off; off >>= 1) v += __shfl_down(v, off, 64);
  __shared__ float s4[4];
  if ((tid & 63) == 0) s4[tid >> 6] = v;
  __syncthreads();
  if (tid == 0)
    atomicAdd(out, (s4[0] + s4[1] + s4[2] + s4[3]) * (1.0f / 8192.0f));
}

extern "C" void kernel_launch(void* const* d_in, const int* in_sizes, int n_in,
                              void* d_out, int out_size, void* d_ws,
                              size_t ws_size, hipStream_t stream) {
  const float* emb_i = (const float*)d_in[0];
  const float* emb_j = (const float*)d_in[1];
  unsigned short* zbF = (unsigned short*)d_ws;           // 4 MB (frag layout)
  float* denomP = (float*)(zbF + (size_t)NROWS * DIM);   // 64*8192 f32 (2 MB)
  float* posv = denomP + (size_t)NCB * NROWS;            // 4096 f32
  float* out = (float*)d_out;

  normalize_kernel<<<NROWS / 16, 256, 0, stream>>>(emb_i, emb_j, zbF, out);
  denom_kernel<<<NTRI, 256, 0, stream>>>(zbF, denomP, posv);
  reduce_kernel<<<NROWS / 256, 256, 0, stream>>>(denomP, posv, out);
}

// Round 3
// 99.273 us; speedup vs baseline: 1.1248x; 1.0058x over previous
//
#include <hip/hip_runtime.h>
#include <math.h>

// NT-Xent (SimCLR) loss. B=4096, D=256, T=0.5.
// R3: denom = LDS-staged A panel (single linear 64 KB global_load_lds copy,
// ONE __syncthreads per block) + B fragments direct from L2 (zbF is 4 MB,
// L2-resident). zbF fragment-native layout (from R2):
//   rg = row>>4, ks = k>>5: offset_shorts = rg*4096 + ks*512
//                                         + ((k>>3)&3)*128 + (row&15)*8 + (k&7)
// A-panel for tile bx = zbF[bx*8*4096 .. +64KB) -- contiguous -> linear LDS
// copy, conflict-free ds_read_b128 fragment reads (lane*16B within 1 KB).
// Rows scaled by sqrt(2/ln2): acc = 2*sim/ln2 -> epilogue exp2(acc) (v_exp,
// no mul). posv holds 2*sim/ln2; reduce weight = 2*ln2.
// T5 s_setprio around MFMA clusters (independent waves, no lockstep).
// LDS 66 KB -> 2 blocks/CU; launch_bounds(256,2).

#define NROWS 8192
#define NHALF 4096
#define DIM   256
#define BM    128
#define BN    128
#define NCB   (NROWS / BN)          // 64 row/col blocks
#define NTRI  (NCB * (NCB + 1) / 2) // 2080 triangle tiles

typedef __attribute__((ext_vector_type(8))) short bf16x8;
typedef __attribute__((ext_vector_type(4))) float f32x4;

static __device__ __forceinline__ unsigned short f2bf(float x) {
  unsigned int u = __float_as_uint(x);
  unsigned int r = (u + 0x7FFFu + ((u >> 16) & 1u)) >> 16;
  return (unsigned short)r;
}

// ---------------- normalize -> fragment-native layout (also zeroes out[0])
__global__ __launch_bounds__(256) void normalize_kernel(
    const float* __restrict__ emb_i, const float* __restrict__ emb_j,
    unsigned short* __restrict__ zbF, float* __restrict__ out) {
  __shared__ unsigned short tile[16 * DIM];  // 8 KB
  if (blockIdx.x == 0 && threadIdx.x == 0) out[0] = 0.f;
  const int w = threadIdx.x >> 6, lane = threadIdx.x & 63;
  const int rg = blockIdx.x;
  #pragma unroll
  for (int rr = 0; rr < 4; ++rr) {
    const int m16 = w * 4 + rr;
    const int row = rg * 16 + m16;
    const float* src = (row < NHALF) ? (emb_i + (size_t)row * DIM)
                                     : (emb_j + (size_t)(row - NHALF) * DIM);
    float4 v = ((const float4*)src)[lane];
    float ss = v.x * v.x + v.y * v.y + v.z * v.z + v.w * v.w;
    #pragma unroll
    for (int off = 32; off; off >>= 1) ss += __shfl_down(ss, off, 64);
    float total = __shfl(ss, 0, 64);
    // sqrt(2/ln2): acc = 2*sim/ln2, so epilogue is exp2(acc) directly.
    float inv = 1.69870011f / fmaxf(sqrtf(total), 1e-12f);
    ushort4 o;
    o.x = f2bf(v.x * inv); o.y = f2bf(v.y * inv);
    o.z = f2bf(v.z * inv); o.w = f2bf(v.w * inv);
    // k = lane*4 -> ks = lane>>3, quad = (lane>>1)&3, j = (lane&1)*4
    const int ks = lane >> 3, quad = (lane >> 1) & 3, jj = (lane & 1) * 4;
    *(ushort4*)&tile[ks * 512 + (quad * 16 + m16) * 8 + jj] = o;
  }
  __syncthreads();
  uint4* dst = (uint4*)(zbF + (size_t)rg * (16 * DIM));
  const uint4* srcT = (const uint4*)tile;
  dst[threadIdx.x] = srcT[threadIdx.x];
  dst[256 + threadIdx.x] = srcT[256 + threadIdx.x];
}

// ------------------------------------------------ MFMA GEMM + exp + sums
__global__ __launch_bounds__(256, 2) void denom_kernel(
    const unsigned short* __restrict__ zbF, float* __restrict__ denomP,
    float* __restrict__ posv) {
  __shared__ unsigned short As[64 * 512];  // 64 KB: full A panel, frag layout
  __shared__ float red[512];               // 2 KB reduction buffer

  // decode triangle tile id -> (bx, by), bx <= by
  int t = blockIdx.x;
  int by = (int)((sqrtf(8.0f * (float)t + 1.0f) - 1.0f) * 0.5f);
  while ((by + 1) * (by + 2) / 2 <= t) ++by;
  while (by * (by + 1) / 2 > t) --by;
  int bx = t - by * (by + 1) / 2;

  const int tid = threadIdx.x;
  const int w = tid >> 6;
  const int lane = tid & 63;
  const int wr = w >> 1, wc = w & 1;  // 2x2 wave grid, 64x64 each
  const int quad = lane >> 4;
  const int m16 = lane & 15;
  const int row0 = bx * BM;
  const int col0 = by * BN;

  // Stage A panel: contiguous 64 KB from zbF (frag layout == linear copy).
  // 64 chunks of 1 KB; wave w stages chunks [w*16, w*16+16).
  {
    const unsigned short* zbA = zbF + (size_t)(bx * 8) * 4096 + lane * 8;
    #pragma unroll
    for (int tt = 0; tt < 16; ++tt) {
      const int chunk = w * 16 + tt;
      __builtin_amdgcn_global_load_lds(
          (const __attribute__((address_space(1))) unsigned int*)(zbA +
                                                                  chunk * 512),
          (__attribute__((address_space(3))) unsigned int*)&As[chunk * 512],
          16, 0, 0);
    }
  }

  // B fragment base pointers (direct from L2)
  const unsigned short* pB[4];
  #pragma unroll
  for (int j = 0; j < 4; ++j)
    pB[j] = zbF + (size_t)(by * 8 + wc * 4 + j) * 4096 + lane * 8;

  f32x4 acc[4][4];
  #pragma unroll
  for (int i = 0; i < 4; ++i)
    #pragma unroll
    for (int j = 0; j < 4; ++j) {
      f32x4 z4 = {0.f, 0.f, 0.f, 0.f};
      acc[i][j] = z4;
    }

#define LOADA(A, ks)                                                       \
  do {                                                                     \
    _Pragma("unroll") for (int i = 0; i < 4; ++i)                          \
        A[i] = *(const bf16x8*)&As[((wr * 4 + i) * 8 + (ks)) * 512 +       \
                                   lane * 8];                              \
  } while (0)

#define LOADB(B, ks)                                                       \
  do {                                                                     \
    _Pragma("unroll") for (int j = 0; j < 4; ++j)                          \
        B[j] = *(const bf16x8*)(pB[j] + (ks) * 512);                       \
  } while (0)

#define MFMA16(A, B)                                                       \
  do {                                                                     \
    __builtin_amdgcn_s_setprio(1);                                         \
    _Pragma("unroll") for (int i = 0; i < 4; ++i)                          \
        _Pragma("unroll") for (int j = 0; j < 4; ++j)                      \
            acc[i][j] = __builtin_amdgcn_mfma_f32_16x16x32_bf16(           \
                A[i], B[j], acc[i][j], 0, 0, 0);                           \
    __builtin_amdgcn_s_setprio(0);                                         \
  } while (0)

  bf16x8 aE[4], bE[4], aO[4], bO[4];
  LOADB(bE, 0);
  LOADB(bO, 1);
  __syncthreads();  // single barrier: stage drain (vmcnt(0)) + B0/B1 ready
  LOADA(aE, 0);
  LOADA(aO, 1);
  #pragma unroll
  for (int k2 = 0; k2 < 4; ++k2) {
    MFMA16(aE, bE);
    if (k2 < 3) {
      LOADB(bE, 2 * k2 + 2);
      LOADA(aE, 2 * k2 + 2);
    }
    MFMA16(aO, bO);
    if (k2 < 3) {
      LOADB(bO, 2 * k2 + 3);
      LOADA(aO, 2 * k2 + 3);
    }
  }
#undef LOADA
#undef LOADB
#undef MFMA16

  // pos extraction: only tiles with col0 == row0 + NHALF hold pair elements.
  // acc = 2*sim/ln2; reduce applies weight 2*ln2.
  if (col0 - row0 == NHALF) {
    #pragma unroll
    for (int i = 0; i < 4; ++i)
      #pragma unroll
      for (int j = 0; j < 4; ++j) {
        int gcol = col0 + wc * 64 + j * 16 + m16;
        #pragma unroll
        for (int r = 0; r < 4; ++r) {
          int grow = row0 + wr * 64 + i * 16 + quad * 4 + r;
          if (gcol - grow == NHALF) posv[grow] = acc[i][j][r];
        }
      }
  }

  // Epilogue: e = exp2(acc) = exp(2*sim). Diagonal tiles (bx==by) pay the
  // grow==gcol compare; off-diagonal tiles skip it.
  float rs[4][4];
  float cs[4] = {0.f, 0.f, 0.f, 0.f};
  #pragma unroll
  for (int i = 0; i < 4; ++i)
    #pragma unroll
    for (int r = 0; r < 4; ++r) rs[i][r] = 0.f;

  if (bx != by) {
    #pragma unroll
    for (int i = 0; i < 4; ++i)
      #pragma unroll
      for (int j = 0; j < 4; ++j)
        #pragma unroll
        for (int r = 0; r < 4; ++r) {
          float e = __builtin_amdgcn_exp2f(acc[i][j][r]);
          rs[i][r] += e;
          cs[j] += e;
        }
  } else {
    #pragma unroll
    for (int i = 0; i < 4; ++i)
      #pragma unroll
      for (int j = 0; j < 4; ++j) {
        int gcol = col0 + wc * 64 + j * 16 + m16;
        #pragma unroll
        for (int r = 0; r < 4; ++r) {
          int grow = row0 + wr * 64 + i * 16 + quad * 4 + r;
          float e =
              (grow == gcol) ? 0.f : __builtin_amdgcn_exp2f(acc[i][j][r]);
          rs[i][r] += e;
          cs[j] += e;
        }
      }
  }

  // rowsum: reduce across the 16 column lanes (same quad)
  #pragma unroll
  for (int i = 0; i < 4; ++i)
    #pragma unroll
    for (int r = 0; r < 4; ++r) {
      float v = rs[i][r];
      v += __shfl_xor(v, 1, 16);
      v += __shfl_xor(v, 2, 16);
      v += __shfl_xor(v, 4, 16);
      v += __shfl_xor(v, 8, 16);
      if (m16 == 0) red[wc * 128 + wr * 64 + i * 16 + quad * 4 + r] = v;
    }
  // colsum: reduce across the 4 quads
  #pragma unroll
  for (int j = 0; j < 4; ++j) {
    float v = cs[j];
    v += __shfl_xor(v, 16, 64);
    v += __shfl_xor(v, 32, 64);
    if (quad == 0) red[256 + wr * 128 + wc * 64 + j * 16 + m16] = v;
  }
  __syncthreads();

  if (tid < 128) {
    denomP[(size_t)by * NROWS + row0 + tid] = red[tid] + red[128 + tid];
  } else if (bx != by) {
    int c = tid - 128;
    denomP[(size_t)bx * NROWS + col0 + c] = red[256 + c] + red[384 + c];
  }
}

// -------------------- denom slots -> -log; + 2*ln2*pos'; atomic into loss
__global__ __launch_bounds__(256) void reduce_kernel(
    const float* __restrict__ denomP, const float* __restrict__ posv,
    float* __restrict__ out) {
  int tid = threadIdx.x;
  int r = blockIdx.x * 256 + tid;  // 32 blocks cover 8192 rows
  float s = 0.f;
  #pragma unroll 8
  for (int b = 0; b < NCB; ++b) s += denomP[(size_t)b * NROWS + r];
  float v = -logf(s);
  // posv = 2*sim/ln2; need 4*sim (covers rows r and r+NHALF) = 2*ln2*posv
  if (r < NHALF) v += 1.38629436112f * posv[r];
  #pragma unroll
  for (int off = 32; off; off >>= 1) v += __shfl_down(v, off, 64);
  __shared__ float s4[4];
  if ((tid & 63) == 0) s4[tid >> 6] = v;
  __syncthreads();
  if (tid == 0)
    atomicAdd(out, (s4[0] + s4[1] + s4[2] + s4[3]) * (1.0f / 8192.0f));
}

extern "C" void kernel_launch(void* const* d_in, const int* in_sizes, int n_in,
                              void* d_out, int out_size, void* d_ws,
                              size_t ws_size, hipStream_t stream) {
  const float* emb_i = (const float*)d_in[0];
  const float* emb_j = (const float*)d_in[1];
  unsigned short* zbF = (unsigned short*)d_ws;           // 4 MB (frag layout)
  float* denomP = (float*)(zbF + (size_t)NROWS * DIM);   // 64*8192 f32 (2 MB)
  float* posv = denomP + (size_t)NCB * NROWS;            // 4096 f32
  float* out = (float*)d_out;

  normalize_kernel<<<NROWS / 16, 256, 0, stream>>>(emb_i, emb_j, zbF, out);
  denom_kernel<<<NTRI, 256, 0, stream>>>(zbF, denomP, posv);
  reduce_kernel<<<NROWS / 256, 256, 0, stream>>>(denomP, posv, out);
}